// Round 1
// baseline (346.659 us; speedup 1.0000x reference)
//
#include <hip/hip_runtime.h>

#define T_DIM 128
#define B_DIM 2048
#define D_DIM 1024
#define KW 8
#define L_DIM 16
#define NCOL (B_DIM * L_DIM)   // 32768 columns total

typedef _Float16 f16x8 __attribute__((ext_vector_type(8)));
typedef _Float16 f16x4 __attribute__((ext_vector_type(4)));
typedef float    f32x16 __attribute__((ext_vector_type(16)));

static __device__ __forceinline__ int imax(int a, int b) { return a > b ? a : b; }
static __device__ __forceinline__ int imin(int a, int b) { return a < b ? a : b; }

// ---------------------------------------------------------------------------
// Kernel 0: convert W1 (fp32 1024x1024 row-major [attn_d][d]) to fp16 in ws
// ---------------------------------------------------------------------------
__global__ void k_cvt_w1(const float* __restrict__ W1, _Float16* __restrict__ W1h) {
    int i = (blockIdx.x * 256 + threadIdx.x) * 4;
    float4 v = *(const float4*)(W1 + i);
    f16x4 h;
    h[0] = (_Float16)v.x; h[1] = (_Float16)v.y;
    h[2] = (_Float16)v.z; h[3] = (_Float16)v.w;
    *(f16x4*)(W1h + i) = h;
}

// ---------------------------------------------------------------------------
// Kernel 1: s_part[mt][col] = sum_{m in m-tile} W2[m]*tanh( (W1 @ x_col)[m] )
// grid = 1024 blocks = 2 m-tiles x 512 col-groups (64 cols each), 256 thr.
// Wave-tile: 128 m x 64 n via 4x2 frags of mfma_f32_32x32x16_f16.
// A-frags from fp16 W1h (global/L2), B-frags gathered from fp32 h_context.
// ---------------------------------------------------------------------------
__launch_bounds__(256, 2)
__global__ void k_gemm(const float* __restrict__ hctx,
                       const int*   __restrict__ offsets,
                       const int*   __restrict__ stc,
                       const int*   __restrict__ sep_l,
                       const _Float16* __restrict__ W1h,
                       const float* __restrict__ W2,
                       float* __restrict__ s_part /* [2][NCOL] */) {
    int bid = blockIdx.x;
    int mt  = bid & 1;          // m-tile: rows [mt*512, mt*512+512)
    int cg  = bid >> 1;         // col-group: cols [cg*64, cg*64+64)
    int tid = threadIdx.x;
    int wid = tid >> 6;         // 0..3
    int lane = tid & 63;
    int lr = lane & 31;
    int hi = lane >> 5;

    int m_wg = mt * 512 + wid * 128;   // this wave's 128 rows (4 frags of 32)

    // ---- per-lane B column setup (nf = 0,1 -> cols lr and 32+lr) ----
    const float* bptr[2];
    int bvalid[2];
#pragma unroll
    for (int nf = 0; nf < 2; ++nf) {
        int col = cg * 64 + nf * 32 + lr;
        int b   = col >> 4;
        int li  = col & 15;
        int off = offsets[b];
        int sep = sep_l[b];
        int st  = stc[b];
        bool in1 = (off <= sep);
        int start = in1 ? imax(off - KW, 0)   : imax(off - KW, sep + 1);
        int end   = in1 ? imin(off + KW, sep) : imin(off + KW, st);
        int idx = start + li;
        bvalid[nf] = (idx < end) ? 1 : 0;
        int tc = imin(imax(idx, 0), T_DIM - 1);
        bptr[nf] = hctx + ((size_t)tc * B_DIM + b) * D_DIM + hi * 8;
    }

    // ---- per-lane A row pointers (4 m-frags) ----
    const _Float16* aptr[4];
#pragma unroll
    for (int f = 0; f < 4; ++f)
        aptr[f] = W1h + (size_t)(m_wg + f * 32 + lr) * D_DIM + hi * 8;

    // ---- accumulators ----
    f32x16 acc[4][2];
#pragma unroll
    for (int f = 0; f < 4; ++f)
#pragma unroll
        for (int nf = 0; nf < 2; ++nf)
#pragma unroll
            for (int i = 0; i < 16; ++i) acc[f][nf][i] = 0.f;

    // ---- K loop: 64 steps of K=16 ----
#pragma unroll 2
    for (int k0 = 0; k0 < D_DIM; k0 += 16) {
        f16x8 a[4];
#pragma unroll
        for (int f = 0; f < 4; ++f)
            a[f] = *(const f16x8*)(aptr[f] + k0);

        f16x8 bb[2];
#pragma unroll
        for (int nf = 0; nf < 2; ++nf) {
            float4 x0 = *(const float4*)(bptr[nf] + k0);
            float4 x1 = *(const float4*)(bptr[nf] + k0 + 4);
            float msk = bvalid[nf] ? 1.f : 0.f;
            f16x8 t;
            t[0] = (_Float16)(x0.x * msk); t[1] = (_Float16)(x0.y * msk);
            t[2] = (_Float16)(x0.z * msk); t[3] = (_Float16)(x0.w * msk);
            t[4] = (_Float16)(x1.x * msk); t[5] = (_Float16)(x1.y * msk);
            t[6] = (_Float16)(x1.z * msk); t[7] = (_Float16)(x1.w * msk);
            bb[nf] = t;
        }

#pragma unroll
        for (int f = 0; f < 4; ++f)
#pragma unroll
            for (int nf = 0; nf < 2; ++nf)
                acc[f][nf] = __builtin_amdgcn_mfma_f32_32x32x16_f16(
                    a[f], bb[nf], acc[f][nf], 0, 0, 0);
    }

    // ---- epilogue: tanh + W2 dot, accumulate per-column partials ----
    // D layout (32x32): col = lane&31, row = (r&3) + 8*(r>>2) + 4*(lane>>5)
    float sp0 = 0.f, sp1 = 0.f;
#pragma unroll
    for (int f = 0; f < 4; ++f) {
#pragma unroll
        for (int rg = 0; rg < 4; ++rg) {
            int mbase = m_wg + f * 32 + rg * 8 + hi * 4;
            float4 w2v = *(const float4*)(W2 + mbase);
            float w2a[4] = {w2v.x, w2v.y, w2v.z, w2v.w};
#pragma unroll
            for (int j = 0; j < 4; ++j) {
                float w2 = w2a[j];
                {
                    float x = acc[f][0][rg * 4 + j];
                    float e = __expf(2.f * x);
                    float th = 1.f - 2.f / (e + 1.f);
                    sp0 += w2 * th;
                }
                {
                    float x = acc[f][1][rg * 4 + j];
                    float e = __expf(2.f * x);
                    float th = 1.f - 2.f / (e + 1.f);
                    sp1 += w2 * th;
                }
            }
        }
    }
    // combine the two half-wave (hi) m-halves
    sp0 += __shfl_xor(sp0, 32, 64);
    sp1 += __shfl_xor(sp1, 32, 64);

    __shared__ float red[4][64];
    if (hi == 0) {
        red[wid][lr]      = sp0;
        red[wid][32 + lr] = sp1;
    }
    __syncthreads();
    if (tid < 64) {
        float s = red[0][tid] + red[1][tid] + red[2][tid] + red[3][tid];
        s_part[(size_t)mt * NCOL + cg * 64 + tid] = s;
    }
}

// ---------------------------------------------------------------------------
// Kernel 2: per-l (16 rows) max and sum-exp over all B columns.
// Also writes s_raw[col] = s_part[0][col] + s_part[1][col].
// grid = 16 blocks x 256 threads.
// ---------------------------------------------------------------------------
__global__ void k_smax1(const float* __restrict__ s_part,
                        float* __restrict__ s_raw,
                        float* __restrict__ lstats /* [32]: 16 max, 16 sum */) {
    int l = blockIdx.x;
    int t = threadIdx.x;
    int lane = t & 63, wid = t >> 6;

    float v[8];
    float mx = -__builtin_inff();
#pragma unroll
    for (int i = 0; i < 8; ++i) {
        int b = i * 256 + t;
        float x = s_part[b * 16 + l] + s_part[NCOL + b * 16 + l];
        v[i] = x;
        s_raw[b * 16 + l] = x;
        mx = fmaxf(mx, x);
    }
#pragma unroll
    for (int d = 1; d < 64; d <<= 1) mx = fmaxf(mx, __shfl_xor(mx, d, 64));
    __shared__ float rm[4];
    if (lane == 0) rm[wid] = mx;
    __syncthreads();
    mx = fmaxf(fmaxf(rm[0], rm[1]), fmaxf(rm[2], rm[3]));

    float se = 0.f;
#pragma unroll
    for (int i = 0; i < 8; ++i) se += __expf(v[i] - mx);
#pragma unroll
    for (int d = 1; d < 64; d <<= 1) se += __shfl_xor(se, d, 64);
    __shared__ float rs[4];
    if (lane == 0) rs[wid] = se;
    __syncthreads();
    if (t == 0) {
        lstats[l]      = mx;
        lstats[16 + l] = rs[0] + rs[1] + rs[2] + rs[3];
    }
}

// ---------------------------------------------------------------------------
// Kernel 3: second (masked) softmax over l + weighted gather-sum to output.
// grid = 2048 blocks (one per batch) x 256 threads (4 floats each over D).
// ---------------------------------------------------------------------------
__global__ void k_out(const float* __restrict__ hctx,
                      const int*   __restrict__ offsets,
                      const int*   __restrict__ stc,
                      const int*   __restrict__ sep_l,
                      const float* __restrict__ s_raw,
                      const float* __restrict__ lstats,
                      float* __restrict__ out) {
    int b = blockIdx.x;
    int t = threadIdx.x;

    int off = offsets[b];
    int sep = sep_l[b];
    int st  = stc[b];
    bool in1 = (off <= sep);
    int start = in1 ? imax(off - KW, 0)   : imax(off - KW, sep + 1);
    int end   = in1 ? imin(off + KW, sep) : imin(off + KW, st);

    float p[16];
    float m2 = -__builtin_inff();
#pragma unroll
    for (int l = 0; l < 16; ++l) {
        bool valid = (start + l) < end;
        float s = s_raw[b * 16 + l];
        float pl = __expf(s - lstats[l]) / lstats[16 + l];
        p[l] = valid ? pl : -__builtin_inff();
        m2 = fmaxf(m2, p[l]);
    }
    float q[16];
    float qs = 0.f;
#pragma unroll
    for (int l = 0; l < 16; ++l) {
        float e = __expf(p[l] - m2);   // exp(-inf) = 0 for invalid
        q[l] = e;
        qs += e;
    }
    float rqs = 1.f / qs;

    float4 acc = {0.f, 0.f, 0.f, 0.f};
#pragma unroll
    for (int l = 0; l < 16; ++l) {
        float wl = q[l] * rqs;
        if (wl > 0.f) {
            int tr = imin(imax(start + l, 0), T_DIM - 1);
            float4 x = *((const float4*)(hctx + ((size_t)tr * B_DIM + b) * D_DIM) + t);
            acc.x += wl * x.x; acc.y += wl * x.y;
            acc.z += wl * x.z; acc.w += wl * x.w;
        }
    }
    *((float4*)(out + (size_t)b * D_DIM) + t) = acc;
}

// ---------------------------------------------------------------------------
extern "C" void kernel_launch(void* const* d_in, const int* in_sizes, int n_in,
                              void* d_out, int out_size, void* d_ws, size_t ws_size,
                              hipStream_t stream) {
    const float* hctx    = (const float*)d_in[0];
    const int*   offsets = (const int*)d_in[1];
    const int*   stc     = (const int*)d_in[2];
    const int*   sep     = (const int*)d_in[3];
    // d_in[4] = no_local (unused by reference)
    const float* W1      = (const float*)d_in[5];
    const float* W2      = (const float*)d_in[6];
    float* out = (float*)d_out;

    char* ws = (char*)d_ws;
    _Float16* W1h   = (_Float16*)ws;                                   // 2 MB
    float*    s_part = (float*)(ws + (2u << 20));                      // 256 KB
    float*    s_raw  = (float*)(ws + (2u << 20) + (256u << 10));       // 128 KB
    float*    lstats = (float*)(ws + (2u << 20) + (256u << 10) + (128u << 10));

    hipLaunchKernelGGL(k_cvt_w1, dim3(1024), dim3(256), 0, stream, W1, W1h);
    hipLaunchKernelGGL(k_gemm,   dim3(1024), dim3(256), 0, stream,
                       hctx, offsets, stc, sep, W1h, W2, s_part);
    hipLaunchKernelGGL(k_smax1,  dim3(16),   dim3(256), 0, stream,
                       s_part, s_raw, lstats);
    hipLaunchKernelGGL(k_out,    dim3(2048), dim3(256), 0, stream,
                       hctx, offsets, stc, sep, s_raw, lstats, out);
}

// Round 2
// 238.959 us; speedup vs baseline: 1.4507x; 1.4507x over previous
//
#include <hip/hip_runtime.h>

#define T_DIM 128
#define B_DIM 2048
#define D_DIM 1024
#define KW 8
#define L_DIM 16
#define NCOL (B_DIM * L_DIM)   // 32768 columns total

typedef _Float16 f16x8 __attribute__((ext_vector_type(8)));
typedef _Float16 f16x4 __attribute__((ext_vector_type(4)));
typedef float    f32x16 __attribute__((ext_vector_type(16)));

static __device__ __forceinline__ int imax(int a, int b) { return a > b ? a : b; }
static __device__ __forceinline__ int imin(int a, int b) { return a < b ? a : b; }

// ---------------------------------------------------------------------------
// Kernel 0: convert W1 (fp32 1024x1024 row-major [attn_d][d]) to fp16 in ws
// ---------------------------------------------------------------------------
__global__ void k_cvt_w1(const float* __restrict__ W1, _Float16* __restrict__ W1h) {
    int i = (blockIdx.x * 256 + threadIdx.x) * 4;
    float4 v = *(const float4*)(W1 + i);
    f16x4 h;
    h[0] = (_Float16)v.x; h[1] = (_Float16)v.y;
    h[2] = (_Float16)v.z; h[3] = (_Float16)v.w;
    *(f16x4*)(W1h + i) = h;
}

// ---------------------------------------------------------------------------
// Kernel 1: gather + cvt to fp16 in MFMA-fragment-interleaved layout:
//   Bh[kc][col][j],  kc in [0,64) (K-chunk of 16), col in [0,32768), j in [0,16)
// Element (kc,col,j) = x[col][k = kc*16 + j], zero if col invalid.
// grid = 512 blocks x 512 threads. Reads: 64B/lane scattered (latency-
// tolerant); writes: 2KB contiguous per wave instruction pair.
// ---------------------------------------------------------------------------
__global__ void k_gather(const float* __restrict__ hctx,
                         const int*   __restrict__ offsets,
                         const int*   __restrict__ stc,
                         const int*   __restrict__ sep_l,
                         _Float16* __restrict__ Bh) {
    int t    = threadIdx.x;
    int lane = t & 63;          // col within group
    int sub  = t >> 6;          // 0..7
    int col  = blockIdx.x * 64 + lane;
    int b    = col >> 4;
    int li   = col & 15;

    int off = offsets[b];
    int sep = sep_l[b];
    int st  = stc[b];
    bool in1 = (off <= sep);
    int start = in1 ? imax(off - KW, 0)   : imax(off - KW, sep + 1);
    int end   = in1 ? imin(off + KW, sep) : imin(off + KW, st);
    int idx = start + li;
    bool valid = (idx < end);
    int tc = imin(imax(idx, 0), T_DIM - 1);
    const float* src = hctx + ((size_t)tc * B_DIM + b) * D_DIM;

#pragma unroll
    for (int c = 0; c < 8; ++c) {
        int kc = sub + c * 8;       // 0..63
        int k0 = kc * 16;
        f16x8 h0 = {}, h1 = {};
        if (valid) {
            float4 x0 = *(const float4*)(src + k0);
            float4 x1 = *(const float4*)(src + k0 + 4);
            float4 x2 = *(const float4*)(src + k0 + 8);
            float4 x3 = *(const float4*)(src + k0 + 12);
            h0[0] = (_Float16)x0.x; h0[1] = (_Float16)x0.y;
            h0[2] = (_Float16)x0.z; h0[3] = (_Float16)x0.w;
            h0[4] = (_Float16)x1.x; h0[5] = (_Float16)x1.y;
            h0[6] = (_Float16)x1.z; h0[7] = (_Float16)x1.w;
            h1[0] = (_Float16)x2.x; h1[1] = (_Float16)x2.y;
            h1[2] = (_Float16)x2.z; h1[3] = (_Float16)x2.w;
            h1[4] = (_Float16)x3.x; h1[5] = (_Float16)x3.y;
            h1[6] = (_Float16)x3.z; h1[7] = (_Float16)x3.w;
        }
        _Float16* dst = Bh + ((size_t)kc * NCOL + col) * 16;
        *(f16x8*)(dst)     = h0;   // j = 0..7  (hi = 0)
        *(f16x8*)(dst + 8) = h1;   // j = 8..15 (hi = 1)
    }
}

// ---------------------------------------------------------------------------
// Kernel 2: s_raw[col] = sum_m W2[m]*tanh( (W1 @ x_col)[m] )
// grid = 512 blocks (one per 64-col group) x 512 threads (8 waves).
// Wave w covers m rows [w*128, w*128+128) x all 64 cols: 4x2 frags of
// mfma_f32_32x32x16_f16. A from L2-resident W1h; B streamed coalesced from
// fragment-interleaved Bh. Register double-buffer, unroll 2.
// ---------------------------------------------------------------------------
__launch_bounds__(512)
__global__ void k_gemm(const _Float16* __restrict__ W1h,
                       const _Float16* __restrict__ Bh,
                       const float* __restrict__ W2,
                       float* __restrict__ s_raw) {
    int cg  = blockIdx.x;       // cols [cg*64, cg*64+64)
    int tid = threadIdx.x;
    int wid = tid >> 6;         // 0..7
    int lane = tid & 63;
    int lr = lane & 31;
    int hi = lane >> 5;

    int m_wg = wid * 128;

    const _Float16* ap  = W1h + (size_t)(m_wg + lr) * D_DIM + hi * 8;
    const _Float16* bp0 = Bh + ((size_t)(cg * 64 + lr)) * 16 + hi * 8;
    const _Float16* bp1 = bp0 + 32 * 16;
    const size_t KSTRIDE = (size_t)NCOL * 16;   // f16 elems per kc plane

    f32x16 acc[4][2];
#pragma unroll
    for (int f = 0; f < 4; ++f)
#pragma unroll
        for (int nf = 0; nf < 2; ++nf)
#pragma unroll
            for (int i = 0; i < 16; ++i) acc[f][nf][i] = 0.f;

    f16x8 a_c[4], b_c[2];
#pragma unroll
    for (int f = 0; f < 4; ++f)
        a_c[f] = *(const f16x8*)(ap + (size_t)f * 32 * D_DIM);
    b_c[0] = *(const f16x8*)(bp0);
    b_c[1] = *(const f16x8*)(bp1);

#pragma unroll 2
    for (int kc = 0; kc < 64; ++kc) {
        int kn = (kc + 1) & 63;      // wraps: last iter reloads kc=0 (unused)
        f16x8 a_n[4], b_n[2];
#pragma unroll
        for (int f = 0; f < 4; ++f)
            a_n[f] = *(const f16x8*)(ap + (size_t)f * 32 * D_DIM + kn * 16);
        b_n[0] = *(const f16x8*)(bp0 + (size_t)kn * KSTRIDE);
        b_n[1] = *(const f16x8*)(bp1 + (size_t)kn * KSTRIDE);

#pragma unroll
        for (int f = 0; f < 4; ++f)
#pragma unroll
            for (int nf = 0; nf < 2; ++nf)
                acc[f][nf] = __builtin_amdgcn_mfma_f32_32x32x16_f16(
                    a_c[f], b_c[nf], acc[f][nf], 0, 0, 0);

#pragma unroll
        for (int f = 0; f < 4; ++f) a_c[f] = a_n[f];
        b_c[0] = b_n[0]; b_c[1] = b_n[1];
    }

    // ---- epilogue: tanh + W2 dot ----
    // D layout (32x32): col = lane&31, row = (r&3) + 8*(r>>2) + 4*(lane>>5)
    float sp0 = 0.f, sp1 = 0.f;
#pragma unroll
    for (int f = 0; f < 4; ++f) {
#pragma unroll
        for (int rg = 0; rg < 4; ++rg) {
            int mbase = m_wg + f * 32 + rg * 8 + hi * 4;
            float4 w2v = *(const float4*)(W2 + mbase);
            float w2a[4] = {w2v.x, w2v.y, w2v.z, w2v.w};
#pragma unroll
            for (int j = 0; j < 4; ++j) {
                float w2 = w2a[j];
                {
                    float x = acc[f][0][rg * 4 + j];
                    float e = __expf(2.f * x);
                    sp0 += w2 * (1.f - 2.f / (e + 1.f));
                }
                {
                    float x = acc[f][1][rg * 4 + j];
                    float e = __expf(2.f * x);
                    sp1 += w2 * (1.f - 2.f / (e + 1.f));
                }
            }
        }
    }
    sp0 += __shfl_xor(sp0, 32, 64);
    sp1 += __shfl_xor(sp1, 32, 64);

    __shared__ float red[8][64];
    if (hi == 0) {
        red[wid][lr]      = sp0;
        red[wid][32 + lr] = sp1;
    }
    __syncthreads();
    if (tid < 64) {
        float s = 0.f;
#pragma unroll
        for (int w = 0; w < 8; ++w) s += red[w][tid];
        s_raw[cg * 64 + tid] = s;
    }
}

// ---------------------------------------------------------------------------
// Kernel 3: per-l (16 rows) max and sum-exp over all B columns.
// grid = 16 blocks x 256 threads.
// ---------------------------------------------------------------------------
__global__ void k_smax1(const float* __restrict__ s_raw,
                        float* __restrict__ lstats /* [32]: 16 max, 16 sum */) {
    int l = blockIdx.x;
    int t = threadIdx.x;
    int lane = t & 63, wid = t >> 6;

    float v[8];
    float mx = -__builtin_inff();
#pragma unroll
    for (int i = 0; i < 8; ++i) {
        int b = i * 256 + t;
        float x = s_raw[b * 16 + l];
        v[i] = x;
        mx = fmaxf(mx, x);
    }
#pragma unroll
    for (int d = 1; d < 64; d <<= 1) mx = fmaxf(mx, __shfl_xor(mx, d, 64));
    __shared__ float rm[4];
    if (lane == 0) rm[wid] = mx;
    __syncthreads();
    mx = fmaxf(fmaxf(rm[0], rm[1]), fmaxf(rm[2], rm[3]));

    float se = 0.f;
#pragma unroll
    for (int i = 0; i < 8; ++i) se += __expf(v[i] - mx);
#pragma unroll
    for (int d = 1; d < 64; d <<= 1) se += __shfl_xor(se, d, 64);
    __shared__ float rs[4];
    if (lane == 0) rs[wid] = se;
    __syncthreads();
    if (t == 0) {
        lstats[l]      = mx;
        lstats[16 + l] = rs[0] + rs[1] + rs[2] + rs[3];
    }
}

// ---------------------------------------------------------------------------
// Kernel 4: second (masked) softmax over l + weighted gather-sum to output.
// grid = 2048 blocks (one per batch) x 256 threads (4 floats each over D).
// ---------------------------------------------------------------------------
__global__ void k_out(const float* __restrict__ hctx,
                      const int*   __restrict__ offsets,
                      const int*   __restrict__ stc,
                      const int*   __restrict__ sep_l,
                      const float* __restrict__ s_raw,
                      const float* __restrict__ lstats,
                      float* __restrict__ out) {
    int b = blockIdx.x;
    int t = threadIdx.x;

    int off = offsets[b];
    int sep = sep_l[b];
    int st  = stc[b];
    bool in1 = (off <= sep);
    int start = in1 ? imax(off - KW, 0)   : imax(off - KW, sep + 1);
    int end   = in1 ? imin(off + KW, sep) : imin(off + KW, st);

    float p[16];
    float m2 = -__builtin_inff();
#pragma unroll
    for (int l = 0; l < 16; ++l) {
        bool valid = (start + l) < end;
        float s = s_raw[b * 16 + l];
        float pl = __expf(s - lstats[l]) / lstats[16 + l];
        p[l] = valid ? pl : -__builtin_inff();
        m2 = fmaxf(m2, p[l]);
    }
    float q[16];
    float qs = 0.f;
#pragma unroll
    for (int l = 0; l < 16; ++l) {
        float e = __expf(p[l] - m2);   // exp(-inf) = 0 for invalid
        q[l] = e;
        qs += e;
    }
    float rqs = 1.f / qs;

    float4 acc = {0.f, 0.f, 0.f, 0.f};
#pragma unroll
    for (int l = 0; l < 16; ++l) {
        float wl = q[l] * rqs;
        if (wl > 0.f) {
            int tr = imin(imax(start + l, 0), T_DIM - 1);
            float4 x = *((const float4*)(hctx + ((size_t)tr * B_DIM + b) * D_DIM) + t);
            acc.x += wl * x.x; acc.y += wl * x.y;
            acc.z += wl * x.z; acc.w += wl * x.w;
        }
    }
    *((float4*)(out + (size_t)b * D_DIM) + t) = acc;
}

// ---------------------------------------------------------------------------
extern "C" void kernel_launch(void* const* d_in, const int* in_sizes, int n_in,
                              void* d_out, int out_size, void* d_ws, size_t ws_size,
                              hipStream_t stream) {
    const float* hctx    = (const float*)d_in[0];
    const int*   offsets = (const int*)d_in[1];
    const int*   stc     = (const int*)d_in[2];
    const int*   sep     = (const int*)d_in[3];
    // d_in[4] = no_local (unused by reference)
    const float* W1      = (const float*)d_in[5];
    const float* W2      = (const float*)d_in[6];
    float* out = (float*)d_out;

    char* ws = (char*)d_ws;
    _Float16* W1h   = (_Float16*)ws;                         // 2 MB
    _Float16* Bh    = (_Float16*)(ws + (2u << 20));          // 64 MB
    float*    s_raw = (float*)(ws + (66u << 20));            // 128 KB
    float*    lstats= (float*)(ws + (66u << 20) + (128u << 10));

    hipLaunchKernelGGL(k_cvt_w1, dim3(1024), dim3(256), 0, stream, W1, W1h);
    hipLaunchKernelGGL(k_gather, dim3(512),  dim3(512), 0, stream,
                       hctx, offsets, stc, sep, Bh);
    hipLaunchKernelGGL(k_gemm,   dim3(512),  dim3(512), 0, stream,
                       W1h, Bh, W2, s_raw);
    hipLaunchKernelGGL(k_smax1,  dim3(16),   dim3(256), 0, stream, s_raw, lstats);
    hipLaunchKernelGGL(k_out,    dim3(2048), dim3(256), 0, stream,
                       hctx, offsets, stc, sep, s_raw, lstats, out);
}

// Round 3
// 207.333 us; speedup vs baseline: 1.6720x; 1.1525x over previous
//
#include <hip/hip_runtime.h>

#define T_DIM 128
#define B_DIM 2048
#define D_DIM 1024
#define KW 8
#define NCOL (B_DIM * 16)      // 32768 columns

// LDS tile geometry (bytes). Layout per buffer: [kcL<8][jh<2][col<64][8 f16]
// plane (kcL) stride padded +16B so staged writes spread banks.
#define PL   2064              // 2*64*8*2 + 16
#define BUFB (8 * PL)          // 16512 B per buffer

typedef _Float16 f16x8 __attribute__((ext_vector_type(8)));
typedef _Float16 f16x4 __attribute__((ext_vector_type(4)));
typedef float    f32x16 __attribute__((ext_vector_type(16)));

static __device__ __forceinline__ int imax(int a, int b) { return a > b ? a : b; }
static __device__ __forceinline__ int imin(int a, int b) { return a < b ? a : b; }

// ---------------------------------------------------------------------------
// Kernel 0: W1 fp32 -> fp16
// ---------------------------------------------------------------------------
__global__ void k_cvt_w1(const float* __restrict__ W1, _Float16* __restrict__ W1h) {
    int i = (blockIdx.x * 256 + threadIdx.x) * 4;
    float4 v = *(const float4*)(W1 + i);
    f16x4 h;
    h[0] = (_Float16)v.x; h[1] = (_Float16)v.y;
    h[2] = (_Float16)v.z; h[3] = (_Float16)v.w;
    *(f16x4*)(W1h + i) = h;
}

// ---------------------------------------------------------------------------
// Kernel 1 (fused gather + GEMM + tanh/W2 epilogue):
//   s_raw[col] = sum_m W2[m] * tanh( sum_k W1[m,k] * x[col,k] )
// grid = 512 blocks (64 cols each) x 512 threads (8 waves).
// Per wave: 128 m x 64 cols (4x2 frags of mfma_f32_32x32x16_f16).
// X staged per 128-k chunk: coalesced fp32 global reads -> regs (issued
// early, T14) -> cvt fp16 + validity mask -> LDS fragment tile (dbuf).
// A (W1h) register-prefetched from L2.
// ---------------------------------------------------------------------------
__launch_bounds__(512, 2)
__global__ void k_gemm(const float* __restrict__ hctx,
                       const int*   __restrict__ offsets,
                       const int*   __restrict__ stc,
                       const int*   __restrict__ sep_l,
                       const _Float16* __restrict__ W1h,
                       const float* __restrict__ W2,
                       float* __restrict__ s_raw) {
    __shared__ __align__(16) char ldsx[2 * BUFB];
    __shared__ float red[8][64];

    int cg   = blockIdx.x;
    int tid  = threadIdx.x;
    int wid  = tid >> 6;
    int lane = tid & 63;
    int lr   = lane & 31;
    int hi   = lane >> 5;

    // ---- staging geometry: wave stages rows [wid*8, wid*8+8); per chunk
    // 4 paired-row loads: rr -> cols (wid*8 + rr*2 + hi), k = k0 + lr*4.
    const float* sbase[4];
    int svalid[4];
    int wr_off[4];
#pragma unroll
    for (int rr = 0; rr < 4; ++rr) {
        int colL = wid * 8 + rr * 2 + hi;
        int col  = cg * 64 + colL;
        int b    = col >> 4;
        int li   = col & 15;
        int off = offsets[b];
        int sep = sep_l[b];
        int st  = stc[b];
        bool in1 = (off <= sep);
        int start = in1 ? imax(off - KW, 0)   : imax(off - KW, sep + 1);
        int end   = in1 ? imin(off + KW, sep) : imin(off + KW, st);
        int idx = start + li;
        svalid[rr] = (idx < end) ? 1 : 0;
        int tc = imin(imax(idx, 0), T_DIM - 1);
        sbase[rr] = hctx + ((size_t)tc * B_DIM + b) * D_DIM + lr * 4;
        // this thread's float4 covers k-sub = lr*4..+3 of the chunk:
        // kcL = lr>>2, jh = (lr>>1)&1, byte j-offset = (lr&1)*8
        wr_off[rr] = (lr >> 2) * PL + ((lr >> 1) & 1) * 1024 + colL * 16 + (lr & 1) * 8;
    }

    // ---- GEMM geometry ----
    const _Float16* ap = W1h + (size_t)(wid * 128 + lr) * D_DIM + hi * 8;
    int rd_off = hi * 1024 + lr * 16;   // + kcL*PL (+512 for col-frag 1)

    f32x16 acc[4][2];
#pragma unroll
    for (int f = 0; f < 4; ++f)
#pragma unroll
        for (int nf = 0; nf < 2; ++nf)
#pragma unroll
            for (int i = 0; i < 16; ++i) acc[f][nf][i] = 0.f;

    // ---- prologue: stage chunk 0 into buf0 ----
    {
        float4 z = {0.f, 0.f, 0.f, 0.f};
#pragma unroll
        for (int rr = 0; rr < 4; ++rr) {
            float4 x = svalid[rr] ? *(const float4*)(sbase[rr]) : z;
            f16x4 h;
            h[0] = (_Float16)x.x; h[1] = (_Float16)x.y;
            h[2] = (_Float16)x.z; h[3] = (_Float16)x.w;
            *(f16x4*)(ldsx + wr_off[rr]) = h;
        }
    }
    __syncthreads();

    f16x8 a_c[4];
#pragma unroll
    for (int f = 0; f < 4; ++f)
        a_c[f] = *(const f16x8*)(ap + (size_t)f * 32 * D_DIM);

    // ---- main loop: 8 chunks of 128 k (8 kc of 16) ----
    for (int c = 0; c < 8; ++c) {
        int bufr = (c & 1) * BUFB;

        // T14: issue next chunk's global loads before compute
        float4 xn[4];
        if (c < 7) {
            int k0 = (c + 1) * 128;
            float4 z = {0.f, 0.f, 0.f, 0.f};
#pragma unroll
            for (int rr = 0; rr < 4; ++rr)
                xn[rr] = svalid[rr] ? *(const float4*)(sbase[rr] + k0) : z;
        }

#pragma unroll
        for (int kcL = 0; kcL < 8; ++kcL) {
            int kc = c * 8 + kcL;
            int kn = (kc + 1) & 63;
            f16x8 a_n[4];
#pragma unroll
            for (int f = 0; f < 4; ++f)
                a_n[f] = *(const f16x8*)(ap + (size_t)f * 32 * D_DIM + kn * 16);

            const char* bp = ldsx + bufr + kcL * PL + rd_off;
            f16x8 b0 = *(const f16x8*)(bp);
            f16x8 b1 = *(const f16x8*)(bp + 512);

#pragma unroll
            for (int f = 0; f < 4; ++f)
                acc[f][0] = __builtin_amdgcn_mfma_f32_32x32x16_f16(
                    a_c[f], b0, acc[f][0], 0, 0, 0);
#pragma unroll
            for (int f = 0; f < 4; ++f)
                acc[f][1] = __builtin_amdgcn_mfma_f32_32x32x16_f16(
                    a_c[f], b1, acc[f][1], 0, 0, 0);
#pragma unroll
            for (int f = 0; f < 4; ++f) a_c[f] = a_n[f];
        }

        // write staged chunk into the other buffer
        if (c < 7) {
            int bufw = ((c + 1) & 1) * BUFB;
#pragma unroll
            for (int rr = 0; rr < 4; ++rr) {
                f16x4 h;
                h[0] = (_Float16)xn[rr].x; h[1] = (_Float16)xn[rr].y;
                h[2] = (_Float16)xn[rr].z; h[3] = (_Float16)xn[rr].w;
                *(f16x4*)(ldsx + bufw + wr_off[rr]) = h;
            }
        }
        __syncthreads();
    }

    // ---- epilogue: tanh + W2 dot ----
    // D layout (32x32): col = lane&31, row = (r&3) + 8*(r>>2) + 4*(lane>>5)
    int m_wg = wid * 128;
    float sp0 = 0.f, sp1 = 0.f;
#pragma unroll
    for (int f = 0; f < 4; ++f) {
#pragma unroll
        for (int rg = 0; rg < 4; ++rg) {
            int mbase = m_wg + f * 32 + rg * 8 + hi * 4;
            float4 w2v = *(const float4*)(W2 + mbase);
            float w2a[4] = {w2v.x, w2v.y, w2v.z, w2v.w};
#pragma unroll
            for (int j = 0; j < 4; ++j) {
                float w2 = w2a[j];
                {
                    float x = acc[f][0][rg * 4 + j];
                    float e = __expf(2.f * x);
                    sp0 += w2 * (1.f - 2.f / (e + 1.f));
                }
                {
                    float x = acc[f][1][rg * 4 + j];
                    float e = __expf(2.f * x);
                    sp1 += w2 * (1.f - 2.f / (e + 1.f));
                }
            }
        }
    }
    sp0 += __shfl_xor(sp0, 32, 64);
    sp1 += __shfl_xor(sp1, 32, 64);

    if (hi == 0) {
        red[wid][lr]      = sp0;
        red[wid][32 + lr] = sp1;
    }
    __syncthreads();
    if (tid < 64) {
        float s = 0.f;
#pragma unroll
        for (int w = 0; w < 8; ++w) s += red[w][tid];
        s_raw[cg * 64 + tid] = s;
    }
}

// ---------------------------------------------------------------------------
// Kernel 2: per-l max and sum-exp over all B columns (softmax over batch).
// ---------------------------------------------------------------------------
__global__ void k_smax1(const float* __restrict__ s_raw,
                        float* __restrict__ lstats /* [32]: 16 max, 16 sum */) {
    int l = blockIdx.x;
    int t = threadIdx.x;
    int lane = t & 63, wid = t >> 6;

    float v[8];
    float mx = -__builtin_inff();
#pragma unroll
    for (int i = 0; i < 8; ++i) {
        int b = i * 256 + t;
        float x = s_raw[b * 16 + l];
        v[i] = x;
        mx = fmaxf(mx, x);
    }
#pragma unroll
    for (int d = 1; d < 64; d <<= 1) mx = fmaxf(mx, __shfl_xor(mx, d, 64));
    __shared__ float rm[4];
    if (lane == 0) rm[wid] = mx;
    __syncthreads();
    mx = fmaxf(fmaxf(rm[0], rm[1]), fmaxf(rm[2], rm[3]));

    float se = 0.f;
#pragma unroll
    for (int i = 0; i < 8; ++i) se += __expf(v[i] - mx);
#pragma unroll
    for (int d = 1; d < 64; d <<= 1) se += __shfl_xor(se, d, 64);
    __shared__ float rs[4];
    if (lane == 0) rs[wid] = se;
    __syncthreads();
    if (t == 0) {
        lstats[l]      = mx;
        lstats[16 + l] = rs[0] + rs[1] + rs[2] + rs[3];
    }
}

// ---------------------------------------------------------------------------
// Kernel 3: masked softmax over l + weighted gather-sum to output.
// ---------------------------------------------------------------------------
__global__ void k_out(const float* __restrict__ hctx,
                      const int*   __restrict__ offsets,
                      const int*   __restrict__ stc,
                      const int*   __restrict__ sep_l,
                      const float* __restrict__ s_raw,
                      const float* __restrict__ lstats,
                      float* __restrict__ out) {
    int b = blockIdx.x;
    int t = threadIdx.x;

    int off = offsets[b];
    int sep = sep_l[b];
    int st  = stc[b];
    bool in1 = (off <= sep);
    int start = in1 ? imax(off - KW, 0)   : imax(off - KW, sep + 1);
    int end   = in1 ? imin(off + KW, sep) : imin(off + KW, st);

    float p[16];
    float m2 = -__builtin_inff();
#pragma unroll
    for (int l = 0; l < 16; ++l) {
        bool valid = (start + l) < end;
        float s = s_raw[b * 16 + l];
        float pl = __expf(s - lstats[l]) / lstats[16 + l];
        p[l] = valid ? pl : -__builtin_inff();
        m2 = fmaxf(m2, p[l]);
    }
    float q[16];
    float qs = 0.f;
#pragma unroll
    for (int l = 0; l < 16; ++l) {
        float e = __expf(p[l] - m2);   // exp(-inf) = 0 for invalid
        q[l] = e;
        qs += e;
    }
    float rqs = 1.f / qs;

    float4 acc = {0.f, 0.f, 0.f, 0.f};
#pragma unroll
    for (int l = 0; l < 16; ++l) {
        float wl = q[l] * rqs;
        if (wl > 0.f) {
            int tr = imin(imax(start + l, 0), T_DIM - 1);
            float4 x = *((const float4*)(hctx + ((size_t)tr * B_DIM + b) * D_DIM) + t);
            acc.x += wl * x.x; acc.y += wl * x.y;
            acc.z += wl * x.z; acc.w += wl * x.w;
        }
    }
    *((float4*)(out + (size_t)b * D_DIM) + t) = acc;
}

// ---------------------------------------------------------------------------
extern "C" void kernel_launch(void* const* d_in, const int* in_sizes, int n_in,
                              void* d_out, int out_size, void* d_ws, size_t ws_size,
                              hipStream_t stream) {
    const float* hctx    = (const float*)d_in[0];
    const int*   offsets = (const int*)d_in[1];
    const int*   stc     = (const int*)d_in[2];
    const int*   sep     = (const int*)d_in[3];
    // d_in[4] = no_local (unused by reference)
    const float* W1      = (const float*)d_in[5];
    const float* W2      = (const float*)d_in[6];
    float* out = (float*)d_out;

    char* ws = (char*)d_ws;
    _Float16* W1h    = (_Float16*)ws;                        // 2 MB
    float*    s_raw  = (float*)(ws + (2u << 20));            // 128 KB
    float*    lstats = (float*)(ws + (2u << 20) + (128u << 10));

    hipLaunchKernelGGL(k_cvt_w1, dim3(1024), dim3(256), 0, stream, W1, W1h);
    hipLaunchKernelGGL(k_gemm,   dim3(512),  dim3(512), 0, stream,
                       hctx, offsets, stc, sep, W1h, W2, s_raw);
    hipLaunchKernelGGL(k_smax1,  dim3(16),   dim3(256), 0, stream, s_raw, lstats);
    hipLaunchKernelGGL(k_out,    dim3(2048), dim3(256), 0, stream,
                       hctx, offsets, stc, sep, s_raw, lstats, out);
}

// Round 4
// 137.449 us; speedup vs baseline: 2.5221x; 1.5084x over previous
//
#include <hip/hip_runtime.h>

#define T_DIM 128
#define B_DIM 2048
#define D_DIM 1024
#define KW 8
#define NCOL (B_DIM * 16)      // 32768 columns

// LDS tile geometry (bytes). Layout per buffer: [kcL<8][jh<2][col<64][8 f16]
// plane (kcL) stride padded +16B so staged writes spread banks.
#define PL   2064              // 2*64*8*2 + 16
#define BUFB (8 * PL)          // 16512 B per buffer

typedef _Float16 f16x8 __attribute__((ext_vector_type(8)));
typedef _Float16 f16x4 __attribute__((ext_vector_type(4)));
typedef float    f32x16 __attribute__((ext_vector_type(16)));

static __device__ __forceinline__ int imax(int a, int b) { return a > b ? a : b; }
static __device__ __forceinline__ int imin(int a, int b) { return a < b ? a : b; }

// ---------------------------------------------------------------------------
// Kernel 0: W1 fp32 [m][k] -> fp16 fragment-interleaved W1f[kc][m][j]
//   W1f[(kc*1024 + m)*16 + j] = W1[m*1024 + kc*16 + j],  kc<64, j<16
// Thread handles one (m, kc): reads 64B coalesced, writes 32B.
// ---------------------------------------------------------------------------
__global__ void k_cvt_w1(const float* __restrict__ W1, _Float16* __restrict__ W1f) {
    int i  = blockIdx.x * 256 + threadIdx.x;   // 65536 threads
    int m  = i >> 6;
    int kc = i & 63;
    const float* src = W1 + (size_t)m * D_DIM + kc * 16;
    float4 x0 = *(const float4*)(src);
    float4 x1 = *(const float4*)(src + 4);
    float4 x2 = *(const float4*)(src + 8);
    float4 x3 = *(const float4*)(src + 12);
    f16x8 h0, h1;
    h0[0] = (_Float16)x0.x; h0[1] = (_Float16)x0.y;
    h0[2] = (_Float16)x0.z; h0[3] = (_Float16)x0.w;
    h0[4] = (_Float16)x1.x; h0[5] = (_Float16)x1.y;
    h0[6] = (_Float16)x1.z; h0[7] = (_Float16)x1.w;
    h1[0] = (_Float16)x2.x; h1[1] = (_Float16)x2.y;
    h1[2] = (_Float16)x2.z; h1[3] = (_Float16)x2.w;
    h1[4] = (_Float16)x3.x; h1[5] = (_Float16)x3.y;
    h1[6] = (_Float16)x3.z; h1[7] = (_Float16)x3.w;
    _Float16* dst = W1f + ((size_t)kc * 1024 + m) * 16;
    *(f16x8*)(dst)     = h0;
    *(f16x8*)(dst + 8) = h1;
}

// ---------------------------------------------------------------------------
// Kernel 1 (fused gather + GEMM + tanh/W2 epilogue):
//   s_raw[col] = sum_m W2[m] * tanh( sum_k W1[m,k] * x[col,k] )
// grid = 512 blocks (64 cols each) x 512 threads (8 waves).
// Per wave: 128 m x 64 cols (4x2 frags of mfma_f32_32x32x16_f16).
// A from fragment-interleaved W1f: each frag load = contiguous 1KB/wave.
// X staged per 128-k chunk via regs -> LDS fragment tile (dbuf, T14 split).
// ---------------------------------------------------------------------------
__launch_bounds__(512, 2)
__global__ void k_gemm(const float* __restrict__ hctx,
                       const int*   __restrict__ offsets,
                       const int*   __restrict__ stc,
                       const int*   __restrict__ sep_l,
                       const _Float16* __restrict__ W1f,
                       const float* __restrict__ W2,
                       float* __restrict__ s_raw) {
    __shared__ __align__(16) char ldsx[2 * BUFB];
    __shared__ float red[8][64];

    int cg   = blockIdx.x;
    int tid  = threadIdx.x;
    int wid  = tid >> 6;
    int lane = tid & 63;
    int lr   = lane & 31;
    int hi   = lane >> 5;

    // ---- staging geometry: wave stages cols [wid*8, wid*8+8); per chunk
    // 4 paired-row loads: rr -> col (wid*8 + rr*2 + hi), k = k0 + lr*4.
    const float* sbase[4];
    int svalid[4];
    int wr_off[4];
#pragma unroll
    for (int rr = 0; rr < 4; ++rr) {
        int colL = wid * 8 + rr * 2 + hi;
        int col  = cg * 64 + colL;
        int b    = col >> 4;
        int li   = col & 15;
        int off = offsets[b];
        int sep = sep_l[b];
        int st  = stc[b];
        bool in1 = (off <= sep);
        int start = in1 ? imax(off - KW, 0)   : imax(off - KW, sep + 1);
        int end   = in1 ? imin(off + KW, sep) : imin(off + KW, st);
        int idx = start + li;
        svalid[rr] = (idx < end) ? 1 : 0;
        int tc = imin(imax(idx, 0), T_DIM - 1);
        sbase[rr] = hctx + ((size_t)tc * B_DIM + b) * D_DIM + lr * 4;
        // this thread's float4 covers k-sub = lr*4..+3 of the chunk:
        // kcL = lr>>2, jh = (lr>>1)&1, byte j-offset = (lr&1)*8
        wr_off[rr] = (lr >> 2) * PL + ((lr >> 1) & 1) * 1024 + colL * 16 + (lr & 1) * 8;
    }

    // ---- GEMM geometry ----
    // A-frag (f, kc): W1f + kc*16384 + (wid*128 + f*32 + lr)*16 + hi*8
    const _Float16* ap = W1f + (size_t)(wid * 128 + lr) * 16 + hi * 8;
    int rd_off = hi * 1024 + lr * 16;   // + kcL*PL (+512 for col-frag 1)

    f32x16 acc[4][2];
#pragma unroll
    for (int f = 0; f < 4; ++f)
#pragma unroll
        for (int nf = 0; nf < 2; ++nf)
#pragma unroll
            for (int i = 0; i < 16; ++i) acc[f][nf][i] = 0.f;

    // ---- prologue: stage chunk 0 into buf0 ----
    {
        float4 z = {0.f, 0.f, 0.f, 0.f};
#pragma unroll
        for (int rr = 0; rr < 4; ++rr) {
            float4 x = svalid[rr] ? *(const float4*)(sbase[rr]) : z;
            f16x4 h;
            h[0] = (_Float16)x.x; h[1] = (_Float16)x.y;
            h[2] = (_Float16)x.z; h[3] = (_Float16)x.w;
            *(f16x4*)(ldsx + wr_off[rr]) = h;
        }
    }
    __syncthreads();

    f16x8 a_c[4];
#pragma unroll
    for (int f = 0; f < 4; ++f)
        a_c[f] = *(const f16x8*)(ap + f * 512);

    // ---- main loop: 8 chunks of 128 k (8 kc of 16) ----
    for (int c = 0; c < 8; ++c) {
        int bufr = (c & 1) * BUFB;

        // T14: issue next chunk's global loads before compute
        float4 xn[4];
        if (c < 7) {
            int k0 = (c + 1) * 128;
            float4 z = {0.f, 0.f, 0.f, 0.f};
#pragma unroll
            for (int rr = 0; rr < 4; ++rr)
                xn[rr] = svalid[rr] ? *(const float4*)(sbase[rr] + k0) : z;
        }

#pragma unroll
        for (int kcL = 0; kcL < 8; ++kcL) {
            int kc = c * 8 + kcL;
            int kn = (kc + 1) & 63;
            f16x8 a_n[4];
#pragma unroll
            for (int f = 0; f < 4; ++f)
                a_n[f] = *(const f16x8*)(ap + (size_t)kn * 16384 + f * 512);

            const char* bp = ldsx + bufr + kcL * PL + rd_off;
            f16x8 b0 = *(const f16x8*)(bp);
            f16x8 b1 = *(const f16x8*)(bp + 512);

#pragma unroll
            for (int f = 0; f < 4; ++f)
                acc[f][0] = __builtin_amdgcn_mfma_f32_32x32x16_f16(
                    a_c[f], b0, acc[f][0], 0, 0, 0);
#pragma unroll
            for (int f = 0; f < 4; ++f)
                acc[f][1] = __builtin_amdgcn_mfma_f32_32x32x16_f16(
                    a_c[f], b1, acc[f][1], 0, 0, 0);
#pragma unroll
            for (int f = 0; f < 4; ++f) a_c[f] = a_n[f];
        }

        // write staged chunk into the other buffer
        if (c < 7) {
            int bufw = ((c + 1) & 1) * BUFB;
#pragma unroll
            for (int rr = 0; rr < 4; ++rr) {
                f16x4 h;
                h[0] = (_Float16)xn[rr].x; h[1] = (_Float16)xn[rr].y;
                h[2] = (_Float16)xn[rr].z; h[3] = (_Float16)xn[rr].w;
                *(f16x4*)(ldsx + bufw + wr_off[rr]) = h;
            }
        }
        __syncthreads();
    }

    // ---- epilogue: tanh + W2 dot ----
    // D layout (32x32): col = lane&31, row = (r&3) + 8*(r>>2) + 4*(lane>>5)
    int m_wg = wid * 128;
    float sp0 = 0.f, sp1 = 0.f;
#pragma unroll
    for (int f = 0; f < 4; ++f) {
#pragma unroll
        for (int rg = 0; rg < 4; ++rg) {
            int mbase = m_wg + f * 32 + rg * 8 + hi * 4;
            float4 w2v = *(const float4*)(W2 + mbase);
            float w2a[4] = {w2v.x, w2v.y, w2v.z, w2v.w};
#pragma unroll
            for (int j = 0; j < 4; ++j) {
                float w2 = w2a[j];
                {
                    float x = acc[f][0][rg * 4 + j];
                    float e = __expf(2.f * x);
                    sp0 += w2 * (1.f - 2.f / (e + 1.f));
                }
                {
                    float x = acc[f][1][rg * 4 + j];
                    float e = __expf(2.f * x);
                    sp1 += w2 * (1.f - 2.f / (e + 1.f));
                }
            }
        }
    }
    sp0 += __shfl_xor(sp0, 32, 64);
    sp1 += __shfl_xor(sp1, 32, 64);

    if (hi == 0) {
        red[wid][lr]      = sp0;
        red[wid][32 + lr] = sp1;
    }
    __syncthreads();
    if (tid < 64) {
        float s = 0.f;
#pragma unroll
        for (int w = 0; w < 8; ++w) s += red[w][tid];
        s_raw[cg * 64 + tid] = s;
    }
}

// ---------------------------------------------------------------------------
// Kernel 2: per-l max and sum-exp over all B columns (softmax over batch).
// ---------------------------------------------------------------------------
__global__ void k_smax1(const float* __restrict__ s_raw,
                        float* __restrict__ lstats /* [32]: 16 max, 16 sum */) {
    int l = blockIdx.x;
    int t = threadIdx.x;
    int lane = t & 63, wid = t >> 6;

    float v[8];
    float mx = -__builtin_inff();
#pragma unroll
    for (int i = 0; i < 8; ++i) {
        int b = i * 256 + t;
        float x = s_raw[b * 16 + l];
        v[i] = x;
        mx = fmaxf(mx, x);
    }
#pragma unroll
    for (int d = 1; d < 64; d <<= 1) mx = fmaxf(mx, __shfl_xor(mx, d, 64));
    __shared__ float rm[4];
    if (lane == 0) rm[wid] = mx;
    __syncthreads();
    mx = fmaxf(fmaxf(rm[0], rm[1]), fmaxf(rm[2], rm[3]));

    float se = 0.f;
#pragma unroll
    for (int i = 0; i < 8; ++i) se += __expf(v[i] - mx);
#pragma unroll
    for (int d = 1; d < 64; d <<= 1) se += __shfl_xor(se, d, 64);
    __shared__ float rs[4];
    if (lane == 0) rs[wid] = se;
    __syncthreads();
    if (t == 0) {
        lstats[l]      = mx;
        lstats[16 + l] = rs[0] + rs[1] + rs[2] + rs[3];
    }
}

// ---------------------------------------------------------------------------
// Kernel 3: masked softmax over l + weighted gather-sum to output.
// ---------------------------------------------------------------------------
__global__ void k_out(const float* __restrict__ hctx,
                      const int*   __restrict__ offsets,
                      const int*   __restrict__ stc,
                      const int*   __restrict__ sep_l,
                      const float* __restrict__ s_raw,
                      const float* __restrict__ lstats,
                      float* __restrict__ out) {
    int b = blockIdx.x;
    int t = threadIdx.x;

    int off = offsets[b];
    int sep = sep_l[b];
    int st  = stc[b];
    bool in1 = (off <= sep);
    int start = in1 ? imax(off - KW, 0)   : imax(off - KW, sep + 1);
    int end   = in1 ? imin(off + KW, sep) : imin(off + KW, st);

    float p[16];
    float m2 = -__builtin_inff();
#pragma unroll
    for (int l = 0; l < 16; ++l) {
        bool valid = (start + l) < end;
        float s = s_raw[b * 16 + l];
        float pl = __expf(s - lstats[l]) / lstats[16 + l];
        p[l] = valid ? pl : -__builtin_inff();
        m2 = fmaxf(m2, p[l]);
    }
    float q[16];
    float qs = 0.f;
#pragma unroll
    for (int l = 0; l < 16; ++l) {
        float e = __expf(p[l] - m2);   // exp(-inf) = 0 for invalid
        q[l] = e;
        qs += e;
    }
    float rqs = 1.f / qs;

    float4 acc = {0.f, 0.f, 0.f, 0.f};
#pragma unroll
    for (int l = 0; l < 16; ++l) {
        float wl = q[l] * rqs;
        if (wl > 0.f) {
            int tr = imin(imax(start + l, 0), T_DIM - 1);
            float4 x = *((const float4*)(hctx + ((size_t)tr * B_DIM + b) * D_DIM) + t);
            acc.x += wl * x.x; acc.y += wl * x.y;
            acc.z += wl * x.z; acc.w += wl * x.w;
        }
    }
    *((float4*)(out + (size_t)b * D_DIM) + t) = acc;
}

// ---------------------------------------------------------------------------
extern "C" void kernel_launch(void* const* d_in, const int* in_sizes, int n_in,
                              void* d_out, int out_size, void* d_ws, size_t ws_size,
                              hipStream_t stream) {
    const float* hctx    = (const float*)d_in[0];
    const int*   offsets = (const int*)d_in[1];
    const int*   stc     = (const int*)d_in[2];
    const int*   sep     = (const int*)d_in[3];
    // d_in[4] = no_local (unused by reference)
    const float* W1      = (const float*)d_in[5];
    const float* W2      = (const float*)d_in[6];
    float* out = (float*)d_out;

    char* ws = (char*)d_ws;
    _Float16* W1f    = (_Float16*)ws;                        // 2 MB
    float*    s_raw  = (float*)(ws + (2u << 20));            // 128 KB
    float*    lstats = (float*)(ws + (2u << 20) + (128u << 10));

    hipLaunchKernelGGL(k_cvt_w1, dim3(256),  dim3(256), 0, stream, W1, W1f);
    hipLaunchKernelGGL(k_gemm,   dim3(512),  dim3(512), 0, stream,
                       hctx, offsets, stc, sep, W1f, W2, s_raw);
    hipLaunchKernelGGL(k_smax1,  dim3(16),   dim3(256), 0, stream, s_raw, lstats);
    hipLaunchKernelGGL(k_out,    dim3(2048), dim3(256), 0, stream,
                       hctx, offsets, stc, sep, s_raw, lstats, out);
}

// Round 5
// 136.849 us; speedup vs baseline: 2.5331x; 1.0044x over previous
//
#include <hip/hip_runtime.h>

#define T_DIM 128
#define B_DIM 2048
#define D_DIM 1024
#define KW 8
#define NCOL (B_DIM * 16)      // 32768 columns

// LDS tile geometry (bytes). Layout per buffer: [kcL<8][jh<2][col<64][8 f16]
// plane (kcL) stride padded +16B so staged writes spread banks.
#define PL   2064              // 2*64*8*2 + 16
#define BUFB (8 * PL)          // 16512 B per buffer

typedef _Float16 f16x8 __attribute__((ext_vector_type(8)));
typedef _Float16 f16x4 __attribute__((ext_vector_type(4)));
typedef float    f32x16 __attribute__((ext_vector_type(16)));

static __device__ __forceinline__ int imax(int a, int b) { return a > b ? a : b; }
static __device__ __forceinline__ int imin(int a, int b) { return a < b ? a : b; }

// ---------------------------------------------------------------------------
// Kernel 0: W1 fp32 [m][k] -> fp16 fragment-interleaved W1f[kc][m][j]
// ---------------------------------------------------------------------------
__global__ void k_cvt_w1(const float* __restrict__ W1, _Float16* __restrict__ W1f) {
    int i  = blockIdx.x * 256 + threadIdx.x;   // 65536 threads
    int m  = i >> 6;
    int kc = i & 63;
    const float* src = W1 + (size_t)m * D_DIM + kc * 16;
    float4 x0 = *(const float4*)(src);
    float4 x1 = *(const float4*)(src + 4);
    float4 x2 = *(const float4*)(src + 8);
    float4 x3 = *(const float4*)(src + 12);
    f16x8 h0, h1;
    h0[0] = (_Float16)x0.x; h0[1] = (_Float16)x0.y;
    h0[2] = (_Float16)x0.z; h0[3] = (_Float16)x0.w;
    h0[4] = (_Float16)x1.x; h0[5] = (_Float16)x1.y;
    h0[6] = (_Float16)x1.z; h0[7] = (_Float16)x1.w;
    h1[0] = (_Float16)x2.x; h1[1] = (_Float16)x2.y;
    h1[2] = (_Float16)x2.z; h1[3] = (_Float16)x2.w;
    h1[4] = (_Float16)x3.x; h1[5] = (_Float16)x3.y;
    h1[6] = (_Float16)x3.z; h1[7] = (_Float16)x3.w;
    _Float16* dst = W1f + ((size_t)kc * 1024 + m) * 16;
    *(f16x8*)(dst)     = h0;
    *(f16x8*)(dst + 8) = h1;
}

// ---------------------------------------------------------------------------
// Kernel 1 (fused gather + GEMM + tanh/W2 epilogue), software-pipelined:
// depth-2 A register prefetch, depth-1 B LDS prefetch.
// ---------------------------------------------------------------------------
__launch_bounds__(512, 2)
__global__ void k_gemm(const float* __restrict__ hctx,
                       const int*   __restrict__ offsets,
                       const int*   __restrict__ stc,
                       const int*   __restrict__ sep_l,
                       const _Float16* __restrict__ W1f,
                       const float* __restrict__ W2,
                       float* __restrict__ s_raw) {
    __shared__ __align__(16) char ldsx[2 * BUFB];
    __shared__ float red[8][64];

    int cg   = blockIdx.x;
    int tid  = threadIdx.x;
    int wid  = tid >> 6;
    int lane = tid & 63;
    int lr   = lane & 31;
    int hi   = lane >> 5;

    // ---- staging geometry ----
    const float* sbase[4];
    int svalid[4];
    int wr_off[4];
#pragma unroll
    for (int rr = 0; rr < 4; ++rr) {
        int colL = wid * 8 + rr * 2 + hi;
        int col  = cg * 64 + colL;
        int b    = col >> 4;
        int li   = col & 15;
        int off = offsets[b];
        int sep = sep_l[b];
        int st  = stc[b];
        bool in1 = (off <= sep);
        int start = in1 ? imax(off - KW, 0)   : imax(off - KW, sep + 1);
        int end   = in1 ? imin(off + KW, sep) : imin(off + KW, st);
        int idx = start + li;
        svalid[rr] = (idx < end) ? 1 : 0;
        int tc = imin(imax(idx, 0), T_DIM - 1);
        sbase[rr] = hctx + ((size_t)tc * B_DIM + b) * D_DIM + lr * 4;
        wr_off[rr] = (lr >> 2) * PL + ((lr >> 1) & 1) * 1024 + colL * 16 + (lr & 1) * 8;
    }

    // ---- GEMM geometry ----
    const _Float16* ap = W1f + (size_t)(wid * 128 + lr) * 16 + hi * 8;
    int rd_off = hi * 1024 + lr * 16;

    f32x16 acc[4][2];
#pragma unroll
    for (int f = 0; f < 4; ++f)
#pragma unroll
        for (int nf = 0; nf < 2; ++nf)
#pragma unroll
            for (int i = 0; i < 16; ++i) acc[f][nf][i] = 0.f;

    // ---- prologue: stage chunk 0 ----
    {
        float4 z = {0.f, 0.f, 0.f, 0.f};
#pragma unroll
        for (int rr = 0; rr < 4; ++rr) {
            float4 x = svalid[rr] ? *(const float4*)(sbase[rr]) : z;
            f16x4 h;
            h[0] = (_Float16)x.x; h[1] = (_Float16)x.y;
            h[2] = (_Float16)x.z; h[3] = (_Float16)x.w;
            *(f16x4*)(ldsx + wr_off[rr]) = h;
        }
    }

    // A pipeline: a0 = a(0), a1 = a(1)  (issued before the barrier)
    f16x8 a0[4], a1[4];
#pragma unroll
    for (int f = 0; f < 4; ++f) a0[f] = *(const f16x8*)(ap + f * 512);
#pragma unroll
    for (int f = 0; f < 4; ++f) a1[f] = *(const f16x8*)(ap + 16384 + f * 512);

    __syncthreads();

    // B pipeline: b0 = b(kcL=0, buf0)
    f16x8 b0[2];
    {
        const char* bp = ldsx + rd_off;
        b0[0] = *(const f16x8*)(bp);
        b0[1] = *(const f16x8*)(bp + 512);
    }

    // ---- main loop: 8 chunks of 128 k ----
    for (int c = 0; c < 8; ++c) {
        int bufr = (c & 1) * BUFB;

        // T14: issue next chunk's global loads before compute
        float4 xn[4];
        if (c < 7) {
            int k0 = (c + 1) * 128;
            float4 z = {0.f, 0.f, 0.f, 0.f};
#pragma unroll
            for (int rr = 0; rr < 4; ++rr)
                xn[rr] = svalid[rr] ? *(const float4*)(sbase[rr] + k0) : z;
        }

#pragma unroll
        for (int kcL = 0; kcL < 8; ++kcL) {
            int kc = c * 8 + kcL;
            int ka = (kc + 2) & 63;          // depth-2 A prefetch target

            f16x8 a2[4];
#pragma unroll
            for (int f = 0; f < 4; ++f)
                a2[f] = *(const f16x8*)(ap + (size_t)ka * 16384 + f * 512);

            f16x8 b1[2];
            if (kcL < 7) {                    // depth-1 B prefetch (same buf)
                const char* bp = ldsx + bufr + (kcL + 1) * PL + rd_off;
                b1[0] = *(const f16x8*)(bp);
                b1[1] = *(const f16x8*)(bp + 512);
            }

#pragma unroll
            for (int f = 0; f < 4; ++f)
                acc[f][0] = __builtin_amdgcn_mfma_f32_32x32x16_f16(
                    a0[f], b0[0], acc[f][0], 0, 0, 0);
#pragma unroll
            for (int f = 0; f < 4; ++f)
                acc[f][1] = __builtin_amdgcn_mfma_f32_32x32x16_f16(
                    a0[f], b0[1], acc[f][1], 0, 0, 0);

#pragma unroll
            for (int f = 0; f < 4; ++f) { a0[f] = a1[f]; a1[f] = a2[f]; }
            if (kcL < 7) { b0[0] = b1[0]; b0[1] = b1[1]; }
        }

        // write staged chunk into the other buffer
        if (c < 7) {
            int bufw = ((c + 1) & 1) * BUFB;
#pragma unroll
            for (int rr = 0; rr < 4; ++rr) {
                f16x4 h;
                h[0] = (_Float16)xn[rr].x; h[1] = (_Float16)xn[rr].y;
                h[2] = (_Float16)xn[rr].z; h[3] = (_Float16)xn[rr].w;
                *(f16x4*)(ldsx + bufw + wr_off[rr]) = h;
            }
        }
        __syncthreads();
        if (c < 7) {    // refill b0 from the fresh buffer (kcL = 0)
            const char* bp = ldsx + ((c + 1) & 1) * BUFB + rd_off;
            b0[0] = *(const f16x8*)(bp);
            b0[1] = *(const f16x8*)(bp + 512);
        }
    }

    // ---- epilogue: tanh + W2 dot ----
    int m_wg = wid * 128;
    float sp0 = 0.f, sp1 = 0.f;
#pragma unroll
    for (int f = 0; f < 4; ++f) {
#pragma unroll
        for (int rg = 0; rg < 4; ++rg) {
            int mbase = m_wg + f * 32 + rg * 8 + hi * 4;
            float4 w2v = *(const float4*)(W2 + mbase);
            float w2a[4] = {w2v.x, w2v.y, w2v.z, w2v.w};
#pragma unroll
            for (int j = 0; j < 4; ++j) {
                float w2 = w2a[j];
                {
                    float x = acc[f][0][rg * 4 + j];
                    float e = __expf(2.f * x);
                    sp0 += w2 * (1.f - 2.f / (e + 1.f));
                }
                {
                    float x = acc[f][1][rg * 4 + j];
                    float e = __expf(2.f * x);
                    sp1 += w2 * (1.f - 2.f / (e + 1.f));
                }
            }
        }
    }
    sp0 += __shfl_xor(sp0, 32, 64);
    sp1 += __shfl_xor(sp1, 32, 64);

    if (hi == 0) {
        red[wid][lr]      = sp0;
        red[wid][32 + lr] = sp1;
    }
    __syncthreads();
    if (tid < 64) {
        float s = 0.f;
#pragma unroll
        for (int w = 0; w < 8; ++w) s += red[w][tid];
        s_raw[cg * 64 + tid] = s;
    }
}

// ---------------------------------------------------------------------------
// Kernel 2: per-l max and sum-exp over all B columns (softmax over batch).
// ---------------------------------------------------------------------------
__global__ void k_smax1(const float* __restrict__ s_raw,
                        float* __restrict__ lstats /* [32]: 16 max, 16 sum */) {
    int l = blockIdx.x;
    int t = threadIdx.x;
    int lane = t & 63, wid = t >> 6;

    float v[8];
    float mx = -__builtin_inff();
#pragma unroll
    for (int i = 0; i < 8; ++i) {
        int b = i * 256 + t;
        float x = s_raw[b * 16 + l];
        v[i] = x;
        mx = fmaxf(mx, x);
    }
#pragma unroll
    for (int d = 1; d < 64; d <<= 1) mx = fmaxf(mx, __shfl_xor(mx, d, 64));
    __shared__ float rm[4];
    if (lane == 0) rm[wid] = mx;
    __syncthreads();
    mx = fmaxf(fmaxf(rm[0], rm[1]), fmaxf(rm[2], rm[3]));

    float se = 0.f;
#pragma unroll
    for (int i = 0; i < 8; ++i) se += __expf(v[i] - mx);
#pragma unroll
    for (int d = 1; d < 64; d <<= 1) se += __shfl_xor(se, d, 64);
    __shared__ float rs[4];
    if (lane == 0) rs[wid] = se;
    __syncthreads();
    if (t == 0) {
        lstats[l]      = mx;
        lstats[16 + l] = rs[0] + rs[1] + rs[2] + rs[3];
    }
}

// ---------------------------------------------------------------------------
// Kernel 3: masked softmax over l + weighted gather-sum to output.
// ---------------------------------------------------------------------------
__global__ void k_out(const float* __restrict__ hctx,
                      const int*   __restrict__ offsets,
                      const int*   __restrict__ stc,
                      const int*   __restrict__ sep_l,
                      const float* __restrict__ s_raw,
                      const float* __restrict__ lstats,
                      float* __restrict__ out) {
    int b = blockIdx.x;
    int t = threadIdx.x;

    int off = offsets[b];
    int sep = sep_l[b];
    int st  = stc[b];
    bool in1 = (off <= sep);
    int start = in1 ? imax(off - KW, 0)   : imax(off - KW, sep + 1);
    int end   = in1 ? imin(off + KW, sep) : imin(off + KW, st);

    float p[16];
    float m2 = -__builtin_inff();
#pragma unroll
    for (int l = 0; l < 16; ++l) {
        bool valid = (start + l) < end;
        float s = s_raw[b * 16 + l];
        float pl = __expf(s - lstats[l]) / lstats[16 + l];
        p[l] = valid ? pl : -__builtin_inff();
        m2 = fmaxf(m2, p[l]);
    }
    float q[16];
    float qs = 0.f;
#pragma unroll
    for (int l = 0; l < 16; ++l) {
        float e = __expf(p[l] - m2);   // exp(-inf) = 0 for invalid
        q[l] = e;
        qs += e;
    }
    float rqs = 1.f / qs;

    float4 acc = {0.f, 0.f, 0.f, 0.f};
#pragma unroll
    for (int l = 0; l < 16; ++l) {
        float wl = q[l] * rqs;
        if (wl > 0.f) {
            int tr = imin(imax(start + l, 0), T_DIM - 1);
            float4 x = *((const float4*)(hctx + ((size_t)tr * B_DIM + b) * D_DIM) + t);
            acc.x += wl * x.x; acc.y += wl * x.y;
            acc.z += wl * x.z; acc.w += wl * x.w;
        }
    }
    *((float4*)(out + (size_t)b * D_DIM) + t) = acc;
}

// ---------------------------------------------------------------------------
extern "C" void kernel_launch(void* const* d_in, const int* in_sizes, int n_in,
                              void* d_out, int out_size, void* d_ws, size_t ws_size,
                              hipStream_t stream) {
    const float* hctx    = (const float*)d_in[0];
    const int*   offsets = (const int*)d_in[1];
    const int*   stc     = (const int*)d_in[2];
    const int*   sep     = (const int*)d_in[3];
    // d_in[4] = no_local (unused by reference)
    const float* W1      = (const float*)d_in[5];
    const float* W2      = (const float*)d_in[6];
    float* out = (float*)d_out;

    char* ws = (char*)d_ws;
    _Float16* W1f    = (_Float16*)ws;                        // 2 MB
    float*    s_raw  = (float*)(ws + (2u << 20));            // 128 KB
    float*    lstats = (float*)(ws + (2u << 20) + (128u << 10));

    hipLaunchKernelGGL(k_cvt_w1, dim3(256),  dim3(256), 0, stream, W1, W1f);
    hipLaunchKernelGGL(k_gemm,   dim3(512),  dim3(512), 0, stream,
                       hctx, offsets, stc, sep, W1f, W2, s_raw);
    hipLaunchKernelGGL(k_smax1,  dim3(16),   dim3(256), 0, stream, s_raw, lstats);
    hipLaunchKernelGGL(k_out,    dim3(2048), dim3(256), 0, stream,
                       hctx, offsets, stc, sep, s_raw, lstats, out);
}